// Round 1
// 482.462 us; speedup vs baseline: 1.0703x; 1.0703x over previous
//
#include <hip/hip_runtime.h>
#include <stdint.h>
#include <stddef.h>

// ============================================================================
// y = x @ W^T + bias via bf16 MFMA, 256x256 tile, 8-wave, 8-phase pipelined
// schedule (learn_hip m201 structure: T2 swizzle + T3/T4 counted vmcnt + T5
// setprio), plain HIP.
//
// SCHEDULE LEDGER (verified on paper; keep in sync if editing):
//   LDS = 8 half-tile slots x 16 KiB = 128 KiB (dynamic, needs attr >64KB).
//     slot = buf*4 + j, j: 0=B.lo 1=B.hi 2=A.lo 3=A.hi ("lo/hi" = 128-row
//     halves of the 256-row A/B tile panels; B is K-major like A).
//   Each wave owns a 128(M) x 64(N) output: wrow=wave>>2 picks A half-slot,
//   wcol=wave&3 picks B half-slot + 64-col range inside it. So a wave's
//   operand footprint is exactly one A slot + one B slot per K-tile.
//   Staging: half-tile = 16 chunks of 1 KiB; wave w stages chunks 2w,2w+1
//   (2 x global_load_lds dwordx4 per thread per half-tile). Half-tiles are
//   staged one-per-phase, 7 ahead of consumption, slot ring mod 8:
//     prologue: B.lo0 B.hi0 A.lo0 A.hi0 B.lo1 B.hi1 A.lo1  -> vmcnt(6), bar
//     iter I:  P1:A.hi(2I+1)->s7  P2:B.lo(2I+2)->s0  P3:B.hi->s1 P4:A.lo->s2
//              P5:A.hi(2I+2)->s3  P6:B.lo(2I+3)->s4  P7:B.hi->s5 P8:A.lo->s6
//   Reads (uniform over waves): P1/P5: A[mh=0] (8 ds_read_b128) + all B (8);
//   P3/P7: A[mh=1] (8). Quadrant MFMA order n-major: (0,0)(0,1)(1,0)(1,1),
//   16 MFMA/phase. Slot-overwrite safety: every slot's LAST read phase is
//   >= 1 barrier before the phase that re-stages it; P1/P3/P5/P7 carry an
//   explicit lgkmcnt(0) BEFORE the closing barrier so reads not consumed by
//   that phase's MFMAs (bfr[2..3]) are drained before the next stage issues.
//   vmcnt(6) at P4/P8 = 3 newest half-tiles (2 loads each) may be in flight;
//   everything needed by the next 4 phases has landed. Stage k-offsets wrap
//   mod K so the count invariant holds on the last iteration (re-stages
//   tiles 0/1 harmlessly).
//   LDS swizzle (proven 0-conflict in prior rounds): row r stores logical
//   16B-granule g at phys granule g^(r&7); staging pre-swizzles the GLOBAL
//   source column (g = (lane&7)^(lane>>3)) so global_load_lds destinations
//   stay lane-contiguous.
// ============================================================================

#define BM 256
#define BN 256
#define BK 64
#define NTHREADS 512

typedef __bf16 bf16x8 __attribute__((ext_vector_type(8)));
typedef float floatx4 __attribute__((ext_vector_type(4)));

// round-to-nearest-even f32 -> bf16 bits
__device__ inline unsigned short f2bf(float f) {
    union { float f; unsigned int u; } v; v.f = f;
    unsigned int u = v.u;
    return (unsigned short)((u + 0x7fffu + ((u >> 16) & 1u)) >> 16);
}

__global__ void cvt_f32_to_bf16(const float* __restrict__ in,
                                unsigned short* __restrict__ out, int n4) {
    int i = blockIdx.x * blockDim.x + threadIdx.x;
    int stride = gridDim.x * blockDim.x;
    for (int idx = i; idx < n4; idx += stride) {
        float4 f = ((const float4*)in)[idx];
        ushort4 o;
        o.x = f2bf(f.x); o.y = f2bf(f.y); o.z = f2bf(f.z); o.w = f2bf(f.w);
        ((ushort4*)out)[idx] = o;
    }
}

#define GLD16(SRC, DST) __builtin_amdgcn_global_load_lds( \
    (const __attribute__((address_space(1))) void*)(SRC),  \
    (__attribute__((address_space(3))) void*)(DST), 16, 0, 0)

#define BARRIER() asm volatile("s_barrier" ::: "memory")
#define LGKM0()   asm volatile("s_waitcnt lgkmcnt(0)" ::: "memory")
#define WAITVM6() asm volatile("s_waitcnt vmcnt(6)" ::: "memory")

__global__ __launch_bounds__(NTHREADS, 2)
void gemm_bt_bias_8ph(const unsigned short* __restrict__ A,
                      const unsigned short* __restrict__ B,
                      const float* __restrict__ bias,
                      float* __restrict__ C,
                      int M, int N, int K) {
    extern __shared__ unsigned short lds[];   // 8 slots x 8192 elem = 128 KiB

    const int tid  = threadIdx.x;
    const int lane = tid & 63;
    const int wave = tid >> 6;          // 0..7
    const int wrow = wave >> 2;         // 0..1 : M half -> A slot
    const int wcol = wave & 3;          // 0..3 : N quarter -> B slot + range

    const int bm = blockIdx.y * BM;
    const int bn = blockIdx.x * BN;

    // ---- staging addressing (pre-swizzled global source) ----
    const int g  = (lane & 7) ^ (lane >> 3);    // logical 16B granule
    const int rs = lane >> 3;                   // row within 8-row chunk
    const int c0 = wave * 2;                    // this wave's chunks c0,c0+1
    const int r0 = c0 * 8 + rs;                 // rows within a 128-row half
    const int r1 = r0 + 8;

    const unsigned short* gBlo0 = B + (size_t)(bn + r0) * K + g * 8;
    const unsigned short* gBlo1 = B + (size_t)(bn + r1) * K + g * 8;
    const unsigned short* gBhi0 = gBlo0 + (size_t)128 * K;
    const unsigned short* gBhi1 = gBlo1 + (size_t)128 * K;
    const unsigned short* gAlo0 = A + (size_t)(bm + r0) * K + g * 8;
    const unsigned short* gAlo1 = A + (size_t)(bm + r1) * K + g * 8;
    const unsigned short* gAhi0 = gAlo0 + (size_t)128 * K;
    const unsigned short* gAhi1 = gAlo1 + (size_t)128 * K;

    unsigned short* const d0 = lds + c0 * 512;  // wave-uniform chunk bases
    unsigned short* const d1 = d0 + 512;

    int kBlo = 0, kBhi = 0, kAlo = 0, kAhi = 0;   // uniform -> SGPR

#define STAGE(P0, P1, KV, SLOT) do {              \
        GLD16((P0) + KV, d0 + (SLOT) * 8192);     \
        GLD16((P1) + KV, d1 + (SLOT) * 8192);     \
        KV += BK; if (KV >= K) KV -= K; } while (0)

    // ---- prologue: half-tiles h0..h6 in ring order ----
    STAGE(gBlo0, gBlo1, kBlo, 0);   // B.lo t0
    STAGE(gBhi0, gBhi1, kBhi, 1);   // B.hi t0
    STAGE(gAlo0, gAlo1, kAlo, 2);   // A.lo t0
    STAGE(gAhi0, gAhi1, kAhi, 3);   // A.hi t0
    STAGE(gBlo0, gBlo1, kBlo, 4);   // B.lo t1
    STAGE(gBhi0, gBhi1, kBhi, 5);   // B.hi t1
    STAGE(gAlo0, gAlo1, kAlo, 6);   // A.lo t1
    WAITVM6();                      // tile 0 (h0..h3) landed
    BARRIER();

    // ---- fragment addressing (same verified swizzle/layout as before) ----
    const int lr = lane & 15;
    const int lq = lane >> 4;
    const int sw = lr & 7;
    const unsigned short* const aslot0 = lds + (2 + wrow) * 8192;
    const unsigned short* const bslot0 = lds + (wcol >> 1) * 8192;
    const unsigned short* const aslot1 = aslot0 + 4 * 8192;
    const unsigned short* const bslot1 = bslot0 + 4 * 8192;
    const int bro = (wcol & 1) * 64;

    floatx4 acc[8][4];
#pragma unroll
    for (int mi = 0; mi < 8; ++mi)
#pragma unroll
        for (int ni = 0; ni < 4; ++ni)
            acc[mi][ni] = (floatx4){0.f, 0.f, 0.f, 0.f};

    bf16x8 af[4][2];    // A frags for one m-half (mh), [mi][ks]
    bf16x8 bfr[4][2];   // B frags for the wave's 64 cols, [ni][ks]

#define LDA_H(BASE, MH) do {                                                   \
    _Pragma("unroll")                                                          \
    for (int mi = 0; mi < 4; ++mi) {                                           \
        _Pragma("unroll")                                                      \
        for (int ks = 0; ks < 2; ++ks)                                         \
            af[mi][ks] = *(const bf16x8*)((BASE) +                             \
                ((MH) * 64 + mi * 16 + lr) * 64 + (((ks << 2) | lq) ^ sw) * 8);\
    } } while (0)

#define LDB_ALL(BASE) do {                                                     \
    _Pragma("unroll")                                                          \
    for (int ni = 0; ni < 4; ++ni) {                                           \
        _Pragma("unroll")                                                      \
        for (int ks = 0; ks < 2; ++ks)                                         \
            bfr[ni][ks] = *(const bf16x8*)((BASE) +                            \
                (bro + ni * 16 + lr) * 64 + (((ks << 2) | lq) ^ sw) * 8);      \
    } } while (0)

#define MFMAQ(MH, NH) do {                                                     \
    __builtin_amdgcn_s_setprio(1);                                             \
    _Pragma("unroll")                                                          \
    for (int mi = 0; mi < 4; ++mi) {                                           \
        _Pragma("unroll")                                                      \
        for (int ni = 0; ni < 2; ++ni) {                                       \
            _Pragma("unroll")                                                  \
            for (int ks = 0; ks < 2; ++ks)                                     \
                acc[(MH) * 4 + mi][(NH) * 2 + ni] =                            \
                    __builtin_amdgcn_mfma_f32_16x16x32_bf16(                   \
                        af[mi][ks], bfr[(NH) * 2 + ni][ks],                    \
                        acc[(MH) * 4 + mi][(NH) * 2 + ni], 0, 0, 0);           \
        } }                                                                    \
    __builtin_amdgcn_s_setprio(0); } while (0)

    const int nIter = K >> 7;   // K/128: 2 K-tiles (BK=64) per iteration
    for (int it = 0; it < nIter; ++it) {
        // ---- phases 1-4: compute buf0 (tile 2it) ----
        // P1
        LDA_H(aslot0, 0);
        LDB_ALL(bslot0);
        STAGE(gAhi0, gAhi1, kAhi, 7);       // A.hi t(2it+1) -> buf1
        BARRIER();
        MFMAQ(0, 0);
        LGKM0();                            // drain bfr[2..3] before s0 restage
        BARRIER();
        // P2
        STAGE(gBlo0, gBlo1, kBlo, 0);       // B.lo t(2it+2) -> buf0
        BARRIER();
        MFMAQ(0, 1);
        BARRIER();
        // P3
        LDA_H(aslot0, 1);
        STAGE(gBhi0, gBhi1, kBhi, 1);       // B.hi t(2it+2)
        BARRIER();
        MFMAQ(1, 0);
        LGKM0();                            // drain A[1] reads before s2 restage
        BARRIER();
        // P4
        STAGE(gAlo0, gAlo1, kAlo, 2);       // A.lo t(2it+2)
        WAITVM6();                          // tile 2it+1 fully landed
        BARRIER();
        MFMAQ(1, 1);
        BARRIER();
        // ---- phases 5-8: compute buf1 (tile 2it+1) ----
        // P5
        LDA_H(aslot1, 0);
        LDB_ALL(bslot1);
        STAGE(gAhi0, gAhi1, kAhi, 3);       // A.hi t(2it+2) -> buf0
        BARRIER();
        MFMAQ(0, 0);
        LGKM0();
        BARRIER();
        // P6
        STAGE(gBlo0, gBlo1, kBlo, 4);       // B.lo t(2it+3) -> buf1
        BARRIER();
        MFMAQ(0, 1);
        BARRIER();
        // P7
        LDA_H(aslot1, 1);
        STAGE(gBhi0, gBhi1, kBhi, 5);       // B.hi t(2it+3)
        BARRIER();
        MFMAQ(1, 0);
        LGKM0();
        BARRIER();
        // P8
        STAGE(gAlo0, gAlo1, kAlo, 6);       // A.lo t(2it+3)
        WAITVM6();                          // tile 2it+2 fully landed
        BARRIER();
        MFMAQ(1, 1);
        BARRIER();
    }
    asm volatile("s_waitcnt vmcnt(0)" ::: "memory");  // drain DMA before exit

    // ---- epilogue: C/D layout col=lane&15, row=lq*4+r (verified) ----
    const int wm = wrow * 128;
    const int wn = wcol * 64;
#pragma unroll
    for (int ni = 0; ni < 4; ++ni) {
        int n = bn + wn + ni * 16 + lr;
        float bv = bias[n];
#pragma unroll
        for (int mi = 0; mi < 8; ++mi) {
            int m0 = bm + wm + mi * 16 + lq * 4;
#pragma unroll
            for (int r = 0; r < 4; ++r)
                C[(size_t)(m0 + r) * N + n] = acc[mi][ni][r] + bv;
        }
    }
#undef STAGE
#undef LDA_H
#undef LDB_ALL
#undef MFMAQ
}

extern "C" void kernel_launch(void* const* d_in, const int* in_sizes, int n_in,
                              void* d_out, int out_size, void* d_ws, size_t ws_size,
                              hipStream_t stream) {
    const float* x    = (const float*)d_in[0];  // [M,K]
    const float* w    = (const float*)d_in[1];  // [N,K]
    const float* bias = (const float*)d_in[2];  // [N]
    float* out = (float*)d_out;

    const int N = in_sizes[2];             // 4096
    const int K = in_sizes[1] / N;         // 4096
    const int M = in_sizes[0] / K;         // 8192

    unsigned short* xb = (unsigned short*)d_ws;              // [M,K] bf16
    unsigned short* wb = xb + (size_t)M * K;                 // [N,K] bf16

    // KEPT IDENTICAL to previous round so (dur_total - gemm_dur) cleanly
    // measures the non-GEMM blob for next-round attribution.
    cvt_f32_to_bf16<<<4096, 256, 0, stream>>>(x, xb, (M * K) / 4);
    cvt_f32_to_bf16<<<4096, 256, 0, stream>>>(w, wb, (N * K) / 4);

    static bool attr_set = false;
    if (!attr_set) {
        (void)hipFuncSetAttribute((const void*)gemm_bt_bias_8ph,
                                  hipFuncAttributeMaxDynamicSharedMemorySize,
                                  131072);
        attr_set = true;
    }

    dim3 grid(N / BN, M / BM);   // (16, 32) = 512 blocks, 1 block/CU
    gemm_bt_bias_8ph<<<grid, NTHREADS, 131072, stream>>>(xb, wb, bias, out, M, N, K);
}